// Round 1
// baseline (385.349 us; speedup 1.0000x reference)
//
#include <hip/hip_runtime.h>
#include <hip/hip_bf16.h>

static constexpr int kB = 8;
static constexpr int kC = 256;
static constexpr int kN = 1024;   // H*W
static constexpr int kG = 32;
static constexpr int kCG = kC / kG;   // 8
static constexpr int kHeads = 4;
static constexpr int kHD = 64;

// ---------------------------------------------------------------------------
// GroupNorm: one block per (b, group). 8 channels x 1024 = 8192 floats.
// ---------------------------------------------------------------------------
__global__ __launch_bounds__(256) void gn_kernel(
    const float* __restrict__ x, const float* __restrict__ gamma,
    const float* __restrict__ beta, float* __restrict__ h) {
  const int bg = blockIdx.x;
  const int b = bg >> 5, g = bg & 31;
  const size_t base = ((size_t)b * kC + (size_t)g * kCG) * kN;
  const float4* __restrict__ x4 = (const float4*)(x + base);
  float4* __restrict__ h4 = (float4*)(h + base);
  const int t = threadIdx.x;

  float4 v[8];
  float s = 0.f, ss = 0.f;
#pragma unroll
  for (int i = 0; i < 8; ++i) {
    v[i] = x4[t + 256 * i];
    s += v[i].x + v[i].y + v[i].z + v[i].w;
    ss += v[i].x * v[i].x + v[i].y * v[i].y + v[i].z * v[i].z + v[i].w * v[i].w;
  }
#pragma unroll
  for (int off = 32; off > 0; off >>= 1) {
    s += __shfl_xor(s, off);
    ss += __shfl_xor(ss, off);
  }
  __shared__ float rs[4], rss[4];
  const int wave = t >> 6, lane = t & 63;
  if (lane == 0) { rs[wave] = s; rss[wave] = ss; }
  __syncthreads();
  s = rs[0] + rs[1] + rs[2] + rs[3];
  ss = rss[0] + rss[1] + rss[2] + rss[3];
  const float mean = s * (1.f / 8192.f);
  const float var = ss * (1.f / 8192.f) - mean * mean;
  const float rinv = rsqrtf(var + 1e-5f);
#pragma unroll
  for (int i = 0; i < 8; ++i) {
    const int ch = g * kCG + i;   // float4 chunk i lies entirely in channel i of the group
    const float ga = gamma[ch] * rinv;
    const float be = beta[ch] - mean * ga;
    float4 o;
    o.x = v[i].x * ga + be;
    o.y = v[i].y * ga + be;
    o.z = v[i].z * ga + be;
    o.w = v[i].w * ga + be;
    h4[t + 256 * i] = o;
  }
}

// ---------------------------------------------------------------------------
// Batched GEMM: out[b][m][n] = sum_k w[m][k] * in[b][k][n] + bias[m] (+res)
// 64x64 tile, K-step 16, 256 threads, 4x4 register tile per thread.
// ---------------------------------------------------------------------------
template <int M>
__global__ __launch_bounds__(256) void gemm_kernel(
    const float* __restrict__ w, const float* __restrict__ bias,
    const float* __restrict__ in, const float* __restrict__ res,
    float* __restrict__ out) {
  __shared__ float As[16][68];   // [k][m], stride 68 -> conflict-free
  __shared__ float Bs[16][64];   // [k][n]
  const int n0 = blockIdx.x * 64, m0 = blockIdx.y * 64, b = blockIdx.z;
  const int t = threadIdx.x;
  const int tx = t & 15, ty = t >> 4;
  const float* __restrict__ wp = w + (size_t)m0 * kC;
  const float* __restrict__ ip = in + (size_t)b * kC * kN + n0;
  float acc[4][4] = {};

  for (int k0 = 0; k0 < kC; k0 += 16) {
    {
      const int kk = t & 15, mm = t >> 4;
#pragma unroll
      for (int i = 0; i < 4; ++i)
        As[kk][mm + 16 * i] = wp[(size_t)(mm + 16 * i) * kC + k0 + kk];
      const int nn = t & 63, k2 = t >> 6;
#pragma unroll
      for (int i = 0; i < 4; ++i)
        Bs[k2 + 4 * i][nn] = ip[(size_t)(k0 + k2 + 4 * i) * kN + nn];
    }
    __syncthreads();
#pragma unroll
    for (int kk = 0; kk < 16; ++kk) {
      const float4 a4 = *(const float4*)&As[kk][ty * 4];
      const float4 b4 = *(const float4*)&Bs[kk][tx * 4];
      const float a[4] = {a4.x, a4.y, a4.z, a4.w};
      const float bb[4] = {b4.x, b4.y, b4.z, b4.w};
#pragma unroll
      for (int i2 = 0; i2 < 4; ++i2)
#pragma unroll
        for (int j2 = 0; j2 < 4; ++j2)
          acc[i2][j2] = fmaf(a[i2], bb[j2], acc[i2][j2]);
    }
    __syncthreads();
  }

#pragma unroll
  for (int i2 = 0; i2 < 4; ++i2) {
    const int m = m0 + ty * 4 + i2;
    const float bv = bias[m];
    const size_t ob = ((size_t)b * M + m) * kN + n0;
#pragma unroll
    for (int j2 = 0; j2 < 4; ++j2) {
      const int n = tx * 4 + j2;
      float r = acc[i2][j2] + bv;
      if (res) r += res[ob + n];
      out[ob + n] = r;
    }
  }
}

// ---------------------------------------------------------------------------
// Attention: one block per (b, head, 16 q-rows). N=1024 keys.
//  phase 1: S[i][j] = (q*scale)^T k   (K streamed from global, Q broadcast LDS)
//  phase 2: row softmax (each wave owns rows 4w..4w+3)
//  phase 3: out[c][i] = sum_j P[i][j] v[c][j]  (V staged in LDS, 32-j chunks)
// LDS: sS 16x1024 (64KB) + union(sQ 64x16, sV 64x36) = 73KB -> 2 blocks/CU.
// ---------------------------------------------------------------------------
__global__ __launch_bounds__(256) void attn_kernel(
    const float* __restrict__ qkv, float* __restrict__ ao) {
  __shared__ float smem[16 * 1024 + 64 * 36];
  typedef float RowS[1024];
  typedef float RowQ[16];
  typedef float RowV[36];
  RowS* sS = (RowS*)smem;
  RowQ* sQ = (RowQ*)(smem + 16 * 1024);   // live in phase 1 only
  RowV* sV = (RowV*)(smem + 16 * 1024);   // live in phase 3 only

  const int i0 = blockIdx.x * 16;
  const int head = blockIdx.y, b = blockIdx.z;
  const float* __restrict__ qp = qkv + ((size_t)(b * 3 + 0) * kC + head * kHD) * kN;
  const float* __restrict__ kp = qkv + ((size_t)(b * 3 + 1) * kC + head * kHD) * kN;
  const float* __restrict__ vp = qkv + ((size_t)(b * 3 + 2) * kC + head * kHD) * kN;
  const int t = threadIdx.x;
  const int lane = t & 63, wave = t >> 6;

  // stage Q (scale folded in)
  {
    const int qi = t & 15, qc0 = t >> 4;
#pragma unroll
    for (int s = 0; s < 4; ++s)
      sQ[qc0 + 16 * s][qi] = qp[(size_t)(qc0 + 16 * s) * kN + i0 + qi] * 0.125f;
  }
  __syncthreads();

  // ---- phase 1: S ----
  {
    float acc[4][16];
#pragma unroll
    for (int jc = 0; jc < 4; ++jc)
#pragma unroll
      for (int i = 0; i < 16; ++i) acc[jc][i] = 0.f;

    for (int c = 0; c < kHD; ++c) {
      const float4 q0 = *(const float4*)&sQ[c][0];
      const float4 q1 = *(const float4*)&sQ[c][4];
      const float4 q2 = *(const float4*)&sQ[c][8];
      const float4 q3 = *(const float4*)&sQ[c][12];
      const float q[16] = {q0.x, q0.y, q0.z, q0.w, q1.x, q1.y, q1.z, q1.w,
                           q2.x, q2.y, q2.z, q2.w, q3.x, q3.y, q3.z, q3.w};
      float kv[4];
#pragma unroll
      for (int jc = 0; jc < 4; ++jc)
        kv[jc] = kp[(size_t)c * kN + t + 256 * jc];
#pragma unroll
      for (int jc = 0; jc < 4; ++jc)
#pragma unroll
        for (int i = 0; i < 16; ++i)
          acc[jc][i] = fmaf(kv[jc], q[i], acc[jc][i]);
    }
#pragma unroll
    for (int jc = 0; jc < 4; ++jc)
#pragma unroll
      for (int i = 0; i < 16; ++i)
        sS[i][t + 256 * jc] = acc[jc][i];
  }
  __syncthreads();

  // ---- phase 2: softmax, wave w owns rows 4w..4w+3 ----
#pragma unroll
  for (int r = 0; r < 4; ++r) {
    const int i = wave * 4 + r;
    float m = -3.4e38f;
    for (int jj = lane; jj < 256; jj += 64) {
      const float4 sv = *(const float4*)&sS[i][jj * 4];
      m = fmaxf(m, fmaxf(fmaxf(sv.x, sv.y), fmaxf(sv.z, sv.w)));
    }
#pragma unroll
    for (int off = 32; off > 0; off >>= 1) m = fmaxf(m, __shfl_xor(m, off));
    float sum = 0.f;
    for (int jj = lane; jj < 256; jj += 64) {
      float4 sv = *(const float4*)&sS[i][jj * 4];
      sv.x = __expf(sv.x - m);
      sv.y = __expf(sv.y - m);
      sv.z = __expf(sv.z - m);
      sv.w = __expf(sv.w - m);
      *(float4*)&sS[i][jj * 4] = sv;
      sum += sv.x + sv.y + sv.z + sv.w;
    }
#pragma unroll
    for (int off = 32; off > 0; off >>= 1) sum += __shfl_xor(sum, off);
    const float rsum = 1.f / sum;
    for (int jj = lane; jj < 256; jj += 64) {
      float4 sv = *(const float4*)&sS[i][jj * 4];
      sv.x *= rsum; sv.y *= rsum; sv.z *= rsum; sv.w *= rsum;
      *(float4*)&sS[i][jj * 4] = sv;
    }
  }
  // NOTE: PV below reads sS row (t>>4) = 4w..4w+3 for wave w — its own rows,
  // so no cross-wave hazard on sS; barriers below protect the sV staging.

  // ---- phase 3: PV ----
  float oacc[4] = {0.f, 0.f, 0.f, 0.f};
  const int pi = t >> 4, cg = t & 15;
  for (int j0 = 0; j0 < kN; j0 += 32) {
    __syncthreads();
    {
      const int jj = t & 31, c0 = t >> 5;   // 2048 elems, 8 per thread
#pragma unroll
      for (int s = 0; s < 8; ++s)
        sV[c0 + 8 * s][jj] = vp[(size_t)(c0 + 8 * s) * kN + j0 + jj];
    }
    __syncthreads();
#pragma unroll
    for (int j = 0; j < 32; j += 4) {
      const float4 p = *(const float4*)&sS[pi][j0 + j];
#pragma unroll
      for (int cc = 0; cc < 4; ++cc) {
        const float4 v4 = *(const float4*)&sV[cg + 16 * cc][j];
        oacc[cc] = fmaf(p.x, v4.x, oacc[cc]);
        oacc[cc] = fmaf(p.y, v4.y, oacc[cc]);
        oacc[cc] = fmaf(p.z, v4.z, oacc[cc]);
        oacc[cc] = fmaf(p.w, v4.w, oacc[cc]);
      }
    }
  }
  float* __restrict__ aop = ao + ((size_t)b * kC + (size_t)head * kHD) * kN;
#pragma unroll
  for (int cc = 0; cc < 4; ++cc)
    aop[(size_t)(cg + 16 * cc) * kN + i0 + pi] = oacc[cc];
}

// ---------------------------------------------------------------------------
extern "C" void kernel_launch(void* const* d_in, const int* in_sizes, int n_in,
                              void* d_out, int out_size, void* d_ws, size_t ws_size,
                              hipStream_t stream) {
  const float* x      = (const float*)d_in[0];
  const float* gamma  = (const float*)d_in[1];
  const float* beta   = (const float*)d_in[2];
  const float* w_qkv  = (const float*)d_in[3];
  const float* b_qkv  = (const float*)d_in[4];
  const float* w_proj = (const float*)d_in[5];
  const float* b_proj = (const float*)d_in[6];
  float* out = (float*)d_out;

  float* h   = (float*)d_ws;                  // 2M floats (8 MB)
  float* qkv = h + (size_t)kB * kC * kN;      // 6M floats (24 MB)
  float* ao  = h;                             // reuse h region: attn reads qkv, writes ao

  hipLaunchKernelGGL(gn_kernel, dim3(kB * kG), dim3(256), 0, stream,
                     x, gamma, beta, h);
  hipLaunchKernelGGL((gemm_kernel<3 * kC>), dim3(kN / 64, (3 * kC) / 64, kB), dim3(256), 0, stream,
                     w_qkv, b_qkv, h, nullptr, qkv);
  hipLaunchKernelGGL(attn_kernel, dim3(kN / 16, kHeads, kB), dim3(256), 0, stream,
                     qkv, ao);
  hipLaunchKernelGGL((gemm_kernel<kC>), dim3(kN / 64, kC / 64, kB), dim3(256), 0, stream,
                     w_proj, b_proj, ao, x, out);
}

// Round 2
// 144.853 us; speedup vs baseline: 2.6603x; 2.6603x over previous
//
#include <hip/hip_runtime.h>
#include <hip/hip_bf16.h>

static constexpr int kB = 8;
static constexpr int kC = 256;
static constexpr int kN = 1024;   // H*W
static constexpr int kG = 32;
static constexpr int kCG = kC / kG;   // 8
static constexpr int kHD = 64;

using s16x8 = __attribute__((ext_vector_type(8))) short;
using f32x4 = __attribute__((ext_vector_type(4))) float;

__device__ inline f32x4 mfma16(s16x8 a, s16x8 b, f32x4 c) {
  return __builtin_amdgcn_mfma_f32_16x16x32_bf16(a, b, c, 0, 0, 0);
}

__device__ inline unsigned short f2bf(float f) {   // RNE, no NaN path needed
  unsigned u = __builtin_bit_cast(unsigned, f);
  u = (u + 0x7fffu + ((u >> 16) & 1u)) >> 16;
  return (unsigned short)u;
}

// ---------------------------------------------------------------------------
// GroupNorm: one block per (b, group). 8 channels x 1024 = 8192 floats.
// ---------------------------------------------------------------------------
__global__ __launch_bounds__(256) void gn_kernel(
    const float* __restrict__ x, const float* __restrict__ gamma,
    const float* __restrict__ beta, float* __restrict__ h) {
  const int bg = blockIdx.x;
  const int b = bg >> 5, g = bg & 31;
  const size_t base = ((size_t)b * kC + (size_t)g * kCG) * kN;
  const float4* __restrict__ x4 = (const float4*)(x + base);
  float4* __restrict__ h4 = (float4*)(h + base);
  const int t = threadIdx.x;

  float4 v[8];
  float s = 0.f, ss = 0.f;
#pragma unroll
  for (int i = 0; i < 8; ++i) {
    v[i] = x4[t + 256 * i];
    s += v[i].x + v[i].y + v[i].z + v[i].w;
    ss += v[i].x * v[i].x + v[i].y * v[i].y + v[i].z * v[i].z + v[i].w * v[i].w;
  }
#pragma unroll
  for (int off = 32; off > 0; off >>= 1) {
    s += __shfl_xor(s, off);
    ss += __shfl_xor(ss, off);
  }
  __shared__ float rs[4], rss[4];
  const int wave = t >> 6, lane = t & 63;
  if (lane == 0) { rs[wave] = s; rss[wave] = ss; }
  __syncthreads();
  s = rs[0] + rs[1] + rs[2] + rs[3];
  ss = rss[0] + rss[1] + rss[2] + rss[3];
  const float mean = s * (1.f / 8192.f);
  const float var = ss * (1.f / 8192.f) - mean * mean;
  const float rinv = rsqrtf(var + 1e-5f);
#pragma unroll
  for (int i = 0; i < 8; ++i) {
    const int ch = g * kCG + i;
    const float ga = gamma[ch] * rinv;
    const float be = beta[ch] - mean * ga;
    float4 o;
    o.x = v[i].x * ga + be;
    o.y = v[i].y * ga + be;
    o.z = v[i].z * ga + be;
    o.w = v[i].w * ga + be;
    h4[t + 256 * i] = o;
  }
}

// ---------------------------------------------------------------------------
// QKV GEMM (fp32 compute): out = w_qkv[768x256] * h[b][256][1024] + bias.
// Epilogue writes bf16: Qt/Kt as [bh][pos][64ch], Vb as [bh][64ch][pos].
// ---------------------------------------------------------------------------
__global__ __launch_bounds__(256) void gemm_qkv_kernel(
    const float* __restrict__ w, const float* __restrict__ bias,
    const float* __restrict__ in, unsigned short* __restrict__ Qt,
    unsigned short* __restrict__ Kt, unsigned short* __restrict__ Vb) {
  __shared__ float As[16][68];
  __shared__ float Bs[16][64];
  const int n0 = blockIdx.x * 64, m0 = blockIdx.y * 64, b = blockIdx.z;
  const int t = threadIdx.x;
  const int tx = t & 15, ty = t >> 4;
  const float* __restrict__ wp = w + (size_t)m0 * kC;
  const float* __restrict__ ip = in + (size_t)b * kC * kN + n0;
  float acc[4][4] = {};

  for (int k0 = 0; k0 < kC; k0 += 16) {
    {
      const int kk = t & 15, mm = t >> 4;
#pragma unroll
      for (int i = 0; i < 4; ++i)
        As[kk][mm + 16 * i] = wp[(size_t)(mm + 16 * i) * kC + k0 + kk];
      const int nn = t & 63, k2 = t >> 6;
#pragma unroll
      for (int i = 0; i < 4; ++i)
        Bs[k2 + 4 * i][nn] = ip[(size_t)(k0 + k2 + 4 * i) * kN + nn];
    }
    __syncthreads();
#pragma unroll
    for (int kk = 0; kk < 16; ++kk) {
      const float4 a4 = *(const float4*)&As[kk][ty * 4];
      const float4 b4 = *(const float4*)&Bs[kk][tx * 4];
      const float a[4] = {a4.x, a4.y, a4.z, a4.w};
      const float bb[4] = {b4.x, b4.y, b4.z, b4.w};
#pragma unroll
      for (int i2 = 0; i2 < 4; ++i2)
#pragma unroll
        for (int j2 = 0; j2 < 4; ++j2)
          acc[i2][j2] = fmaf(a[i2], bb[j2], acc[i2][j2]);
    }
    __syncthreads();
  }

  const int mglob = m0 + ty * 4;
  const int tensor = mglob >> 8;          // 0=Q,1=K,2=V (tile fully inside one)
  const int head = (mglob >> 6) & 3;
  const int ch = mglob & 63;              // ch..ch+3
  const size_t bh = (size_t)b * 4 + head;
  float bv[4];
#pragma unroll
  for (int i2 = 0; i2 < 4; ++i2) bv[i2] = bias[mglob + i2];
  const int nb = n0 + tx * 4;

  if (tensor == 2) {
    unsigned short* vp = Vb + (bh * 64 + ch) * 1024 + nb;
#pragma unroll
    for (int i2 = 0; i2 < 4; ++i2) {
      ushort4 w4;
      w4.x = f2bf(acc[i2][0] + bv[i2]);
      w4.y = f2bf(acc[i2][1] + bv[i2]);
      w4.z = f2bf(acc[i2][2] + bv[i2]);
      w4.w = f2bf(acc[i2][3] + bv[i2]);
      *(ushort4*)(vp + (size_t)i2 * 1024) = w4;
    }
  } else {
    unsigned short* qp = (tensor ? Kt : Qt) + (bh * 1024 + nb) * 64 + ch;
#pragma unroll
    for (int j2 = 0; j2 < 4; ++j2) {
      ushort4 w4;
      w4.x = f2bf(acc[0][j2] + bv[0]);
      w4.y = f2bf(acc[1][j2] + bv[1]);
      w4.z = f2bf(acc[2][j2] + bv[2]);
      w4.w = f2bf(acc[3][j2] + bv[3]);
      *(ushort4*)(qp + (size_t)j2 * 64) = w4;
    }
  }
}

// ---------------------------------------------------------------------------
// MFMA flash attention. Grid (16 q-blocks, 4 heads, 8 b), 4 waves/block,
// each wave owns 16 q rows independently (no barriers).
//  S^T-tile = mfma(A=K-frag, B=Q-frag): lane holds col q=lane&15,
//  rows j = 16*mt + 4*grp + reg  (HW-measured C/D layout).
//  Online softmax lane-local + shfl_xor(16/32); P -> LDS (per-wave) -> B-frag.
//  O[ch][q] += mfma(A=V-frag, B=P-frag); same col=q layout -> local rescale.
// ---------------------------------------------------------------------------
__global__ __launch_bounds__(256) void attn_mfma_kernel(
    const unsigned short* __restrict__ Qt, const unsigned short* __restrict__ Kt,
    const unsigned short* __restrict__ Vb, float* __restrict__ ao) {
  __shared__ unsigned short P_lds[4][16][56];   // stride 56: 16B-aligned rows, <=2-way
  const int t = threadIdx.x;
  const int wave = t >> 6, lane = t & 63;
  const int li = lane & 15, grp = lane >> 4;
  const int head = blockIdx.y, b = blockIdx.z;
  const int bh = b * 4 + head;
  const int q0 = blockIdx.x * 64 + wave * 16;
  const unsigned short* Qp = Qt + (size_t)bh * 65536;
  const unsigned short* Kp = Kt + (size_t)bh * 65536;
  const unsigned short* Vp = Vb + (size_t)bh * 65536;

  s16x8 qf[2];
#pragma unroll
  for (int ks = 0; ks < 2; ++ks)
    qf[ks] = *(const s16x8*)(Qp + (q0 + li) * 64 + ks * 32 + grp * 8);

  f32x4 O[4];
#pragma unroll
  for (int ct = 0; ct < 4; ++ct) O[ct] = f32x4{0.f, 0.f, 0.f, 0.f};
  float m_run = -3.0e38f, l_run = 0.f;

  s16x8 kf[2][2];
#pragma unroll
  for (int mt = 0; mt < 2; ++mt)
#pragma unroll
    for (int ks = 0; ks < 2; ++ks)
      kf[mt][ks] = *(const s16x8*)(Kp + (mt * 16 + li) * 64 + ks * 32 + grp * 8);

  for (int it = 0; it < 32; ++it) {
    const int kv = it * 32;
    // V frags for this tile (issue early; waited at the PV mfma)
    s16x8 vf[4];
#pragma unroll
    for (int ct = 0; ct < 4; ++ct)
      vf[ct] = *(const s16x8*)(Vp + (size_t)(ct * 16 + li) * 1024 + kv + grp * 8);
    // prefetch next K frags
    s16x8 kn[2][2];
    if (it < 31) {
#pragma unroll
      for (int mt = 0; mt < 2; ++mt)
#pragma unroll
        for (int ks = 0; ks < 2; ++ks)
          kn[mt][ks] = *(const s16x8*)(Kp + (kv + 32 + mt * 16 + li) * 64 + ks * 32 + grp * 8);
    }
    // S^T = K^T-tile . Q-tile  (rows j, col q)
    f32x4 s[2];
#pragma unroll
    for (int mt = 0; mt < 2; ++mt) {
      s[mt] = mfma16(kf[mt][0], qf[0], f32x4{0.f, 0.f, 0.f, 0.f});
      s[mt] = mfma16(kf[mt][1], qf[1], s[mt]);
    }
    // online softmax (scale 1/8 folded into exp args)
    float pm = fmaxf(fmaxf(fmaxf(s[0][0], s[0][1]), fmaxf(s[0][2], s[0][3])),
                     fmaxf(fmaxf(s[1][0], s[1][1]), fmaxf(s[1][2], s[1][3])));
    pm = fmaxf(pm, __shfl_xor(pm, 16));
    pm = fmaxf(pm, __shfl_xor(pm, 32));
    const float mnew = fmaxf(m_run, pm);
    const float f = __expf((m_run - mnew) * 0.125f);
    m_run = mnew;
    l_run *= f;
#pragma unroll
    for (int ct = 0; ct < 4; ++ct) O[ct] *= f;
    float p[2][4];
#pragma unroll
    for (int mt = 0; mt < 2; ++mt)
#pragma unroll
      for (int r = 0; r < 4; ++r) {
        p[mt][r] = __expf((s[mt][r] - mnew) * 0.125f);
        l_run += p[mt][r];
      }
    // pack P (bf16) -> per-wave LDS at [q][j] (j = 16*mt + 4*grp + reg)
#pragma unroll
    for (int mt = 0; mt < 2; ++mt) {
      ushort4 w4;
      w4.x = f2bf(p[mt][0]);
      w4.y = f2bf(p[mt][1]);
      w4.z = f2bf(p[mt][2]);
      w4.w = f2bf(p[mt][3]);
      *(ushort4*)&P_lds[wave][li][16 * mt + 4 * grp] = w4;
    }
    const s16x8 pf = *(const s16x8*)&P_lds[wave][li][8 * grp];
#pragma unroll
    for (int ct = 0; ct < 4; ++ct)
      O[ct] = mfma16(vf[ct], pf, O[ct]);
#pragma unroll
    for (int mt = 0; mt < 2; ++mt)
#pragma unroll
      for (int ks = 0; ks < 2; ++ks)
        kf[mt][ks] = kn[mt][ks];
  }

  float lt = l_run;
  lt += __shfl_xor(lt, 16);
  lt += __shfl_xor(lt, 32);
  const float rinv = 1.f / lt;
  float* aop = ao + ((size_t)b * kC + head * kHD) * kN + q0 + li;
#pragma unroll
  for (int ct = 0; ct < 4; ++ct)
#pragma unroll
    for (int r = 0; r < 4; ++r)
      aop[(size_t)(ct * 16 + 4 * grp + r) * kN] = O[ct][r] * rinv;
}

// ---------------------------------------------------------------------------
// Proj GEMM (fp32) with residual: out = w_proj * ao + b_proj + x
// ---------------------------------------------------------------------------
__global__ __launch_bounds__(256) void gemm_proj_kernel(
    const float* __restrict__ w, const float* __restrict__ bias,
    const float* __restrict__ in, const float* __restrict__ res,
    float* __restrict__ out) {
  __shared__ float As[16][68];
  __shared__ float Bs[16][64];
  const int n0 = blockIdx.x * 64, m0 = blockIdx.y * 64, b = blockIdx.z;
  const int t = threadIdx.x;
  const int tx = t & 15, ty = t >> 4;
  const float* __restrict__ wp = w + (size_t)m0 * kC;
  const float* __restrict__ ip = in + (size_t)b * kC * kN + n0;
  float acc[4][4] = {};

  for (int k0 = 0; k0 < kC; k0 += 16) {
    {
      const int kk = t & 15, mm = t >> 4;
#pragma unroll
      for (int i = 0; i < 4; ++i)
        As[kk][mm + 16 * i] = wp[(size_t)(mm + 16 * i) * kC + k0 + kk];
      const int nn = t & 63, k2 = t >> 6;
#pragma unroll
      for (int i = 0; i < 4; ++i)
        Bs[k2 + 4 * i][nn] = ip[(size_t)(k0 + k2 + 4 * i) * kN + nn];
    }
    __syncthreads();
#pragma unroll
    for (int kk = 0; kk < 16; ++kk) {
      const float4 a4 = *(const float4*)&As[kk][ty * 4];
      const float4 b4 = *(const float4*)&Bs[kk][tx * 4];
      const float a[4] = {a4.x, a4.y, a4.z, a4.w};
      const float bb[4] = {b4.x, b4.y, b4.z, b4.w};
#pragma unroll
      for (int i2 = 0; i2 < 4; ++i2)
#pragma unroll
        for (int j2 = 0; j2 < 4; ++j2)
          acc[i2][j2] = fmaf(a[i2], bb[j2], acc[i2][j2]);
    }
    __syncthreads();
  }

#pragma unroll
  for (int i2 = 0; i2 < 4; ++i2) {
    const int m = m0 + ty * 4 + i2;
    const float bv = bias[m];
    const size_t ob = ((size_t)b * kC + m) * kN + n0;
#pragma unroll
    for (int j2 = 0; j2 < 4; ++j2) {
      const int n = tx * 4 + j2;
      out[ob + n] = acc[i2][j2] + bv + res[ob + n];
    }
  }
}

// ---------------------------------------------------------------------------
extern "C" void kernel_launch(void* const* d_in, const int* in_sizes, int n_in,
                              void* d_out, int out_size, void* d_ws, size_t ws_size,
                              hipStream_t stream) {
  const float* x      = (const float*)d_in[0];
  const float* gamma  = (const float*)d_in[1];
  const float* beta   = (const float*)d_in[2];
  const float* w_qkv  = (const float*)d_in[3];
  const float* b_qkv  = (const float*)d_in[4];
  const float* w_proj = (const float*)d_in[5];
  const float* b_proj = (const float*)d_in[6];
  float* out = (float*)d_out;

  float* h = (float*)d_ws;                              // 2M f32 (8 MB)
  unsigned short* Qt = (unsigned short*)(h + (size_t)kB * kC * kN);  // 4 MB
  unsigned short* Kt = Qt + (size_t)kB * 4 * kN * kHD;               // 4 MB
  unsigned short* Vb = Kt + (size_t)kB * 4 * kN * kHD;               // 4 MB
  float* ao = h;   // h dead after QKV GEMM; attn writes ao here

  hipLaunchKernelGGL(gn_kernel, dim3(kB * kG), dim3(256), 0, stream,
                     x, gamma, beta, h);
  hipLaunchKernelGGL(gemm_qkv_kernel, dim3(kN / 64, (3 * kC) / 64, kB), dim3(256), 0, stream,
                     w_qkv, b_qkv, h, Qt, Kt, Vb);
  hipLaunchKernelGGL(attn_mfma_kernel, dim3(kN / 64, 4, kB), dim3(256), 0, stream,
                     Qt, Kt, Vb, ao);
  hipLaunchKernelGGL(gemm_proj_kernel, dim3(kN / 64, kC / 64, kB), dim3(256), 0, stream,
                     w_proj, b_proj, ao, x, out);
}

// Round 3
// 52.824 us; speedup vs baseline: 7.2950x; 2.7422x over previous
//
#include <hip/hip_runtime.h>
#include <hip/hip_bf16.h>

static constexpr int kB = 8;
static constexpr int kC = 256;
static constexpr int kN = 1024;   // H*W
static constexpr int kHD = 64;

using s16x8 = __attribute__((ext_vector_type(8))) short;
using f32x4 = __attribute__((ext_vector_type(4))) float;

__device__ inline f32x4 mfma16(s16x8 a, s16x8 b, f32x4 c) {
  return __builtin_amdgcn_mfma_f32_16x16x32_bf16(a, b, c, 0, 0, 0);
}

__device__ inline unsigned short f2bf(float f) {   // RNE
  unsigned u = __builtin_bit_cast(unsigned, f);
  u = (u + 0x7fffu + ((u >> 16) & 1u)) >> 16;
  return (unsigned short)u;
}

// ---------------------------------------------------------------------------
// Pack fp32 weights into MFMA A-frag layout:
//   frag(Mt,kt): lane(li,grp) holds W[Mt*16+li][kt*32+grp*8 .. +8]  (16B)
// w_qkv: 48 Mt * 8 kt = 384 frags (24576 chunks); w_proj: 128 frags (8192).
// ---------------------------------------------------------------------------
__global__ __launch_bounds__(256) void pack_w_kernel(
    const float* __restrict__ wq, const float* __restrict__ wp,
    unsigned short* __restrict__ Wqp, unsigned short* __restrict__ Wpp) {
  const int tid = blockIdx.x * 256 + threadIdx.x;   // 0..32767
  const float* src;
  unsigned short* dst;
  if (tid < 24576) {
    const int fragid = tid >> 6, lane = tid & 63;
    const int Mt = fragid >> 3, kt = fragid & 7;
    const int li = lane & 15, g = lane >> 4;
    src = wq + (size_t)(Mt * 16 + li) * 256 + kt * 32 + g * 8;
    dst = Wqp + (size_t)tid * 8;
  } else {
    const int id = tid - 24576;
    const int fragid = id >> 6, lane = id & 63;
    const int Mt = fragid >> 3, kt = fragid & 7;
    const int li = lane & 15, g = lane >> 4;
    src = wp + (size_t)(Mt * 16 + li) * 256 + kt * 32 + g * 8;
    dst = Wpp + (size_t)id * 8;
  }
  const float4 f0 = *(const float4*)src;
  const float4 f1 = *(const float4*)(src + 4);
  ushort4 o0, o1;
  o0.x = f2bf(f0.x); o0.y = f2bf(f0.y); o0.z = f2bf(f0.z); o0.w = f2bf(f0.w);
  o1.x = f2bf(f1.x); o1.y = f2bf(f1.y); o1.z = f2bf(f1.z); o1.w = f2bf(f1.w);
  *(ushort4*)dst = o0;
  *(ushort4*)(dst + 4) = o1;
}

// ---------------------------------------------------------------------------
// GroupNorm -> hTp packed B-frags: frag(b,nt,kt): lane(li,grp) holds
//   h[b][kt*32+grp*8 .. +8][nt*16+li]  (8 channels, one position).
// Block (b,g): group g covers channels 8g..8g+7 = exactly k-chunk g.
// ---------------------------------------------------------------------------
__global__ __launch_bounds__(256) void gn_kernel(
    const float* __restrict__ x, const float* __restrict__ gamma,
    const float* __restrict__ beta, unsigned short* __restrict__ hTp) {
  const int bg = blockIdx.x;
  const int b = bg >> 5, g = bg & 31;
  const size_t base = ((size_t)b * kC + (size_t)g * 8) * kN;
  const float4* __restrict__ x4 = (const float4*)(x + base);
  const int t = threadIdx.x;

  float vv[8][4];
  float s = 0.f, ss = 0.f;
#pragma unroll
  for (int i = 0; i < 8; ++i) {
    const float4 v = x4[t + 256 * i];
    vv[i][0] = v.x; vv[i][1] = v.y; vv[i][2] = v.z; vv[i][3] = v.w;
    s += v.x + v.y + v.z + v.w;
    ss += v.x * v.x + v.y * v.y + v.z * v.z + v.w * v.w;
  }
#pragma unroll
  for (int off = 32; off > 0; off >>= 1) {
    s += __shfl_xor(s, off);
    ss += __shfl_xor(ss, off);
  }
  __shared__ float rs[4], rss[4];
  const int wave = t >> 6, lane = t & 63;
  if (lane == 0) { rs[wave] = s; rss[wave] = ss; }
  __syncthreads();
  s = rs[0] + rs[1] + rs[2] + rs[3];
  ss = rss[0] + rss[1] + rss[2] + rss[3];
  const float mean = s * (1.f / 8192.f);
  const float var = ss * (1.f / 8192.f) - mean * mean;
  const float rinv = rsqrtf(var + 1e-5f);
  float ga[8], be[8];
#pragma unroll
  for (int i = 0; i < 8; ++i) {
    ga[i] = gamma[g * 8 + i] * rinv;
    be[i] = beta[g * 8 + i] - mean * ga[i];
  }
  const int kt = g >> 2, gq = g & 3;
#pragma unroll
  for (int r = 0; r < 4; ++r) {
    const int pos = 4 * t + r;
    const int nt = pos >> 4, lp = pos & 15;
    unsigned short* dst =
        hTp + ((size_t)((b * 64 + nt) * 8 + kt) * 64 + (gq * 16 + lp)) * 8;
    ushort4 o0, o1;
    o0.x = f2bf(vv[0][r] * ga[0] + be[0]);
    o0.y = f2bf(vv[1][r] * ga[1] + be[1]);
    o0.z = f2bf(vv[2][r] * ga[2] + be[2]);
    o0.w = f2bf(vv[3][r] * ga[3] + be[3]);
    o1.x = f2bf(vv[4][r] * ga[4] + be[4]);
    o1.y = f2bf(vv[5][r] * ga[5] + be[5]);
    o1.z = f2bf(vv[6][r] * ga[6] + be[6]);
    o1.w = f2bf(vv[7][r] * ga[7] + be[7]);
    *(ushort4*)dst = o0;
    *(ushort4*)(dst + 4) = o1;
  }
}

// ---------------------------------------------------------------------------
// LDS-free bf16 MFMA GEMM, all operands packed frags in global (L1/L2).
// Block: 256 thr = 4 waves (2m x 2n), tile 128m x 64n; wave 64m x 32n; K=256.
//  - qkv (!PROJ): M=768; mb 0,1=Q  2,3=K  4,5=V. Q/K: D[m=ch][n=pos], store
//    frag-packed Qp/Kp. V: swapped mfma -> D[pos][ch], store frag-packed Vp.
//  - PROJ: M=256, fp32 out + bias + residual.
// ---------------------------------------------------------------------------
template <int MT128, bool PROJ>
__global__ __launch_bounds__(256) void gemm_pk_kernel(
    const unsigned short* __restrict__ Wp, const float* __restrict__ bias,
    const unsigned short* __restrict__ Bp,
    unsigned short* __restrict__ Qp, unsigned short* __restrict__ Kp,
    unsigned short* __restrict__ Vp,
    const float* __restrict__ res, float* __restrict__ outp) {
  constexpr int CPX = MT128 * 16;
  const int bid = blockIdx.x;
  const int swz = (bid & 7) * CPX + (bid >> 3);
  const int b = swz / CPX, rr = swz % CPX;
  const int mb = rr >> 4, nb = rr & 15;
  const int t = threadIdx.x;
  const int wave = t >> 6, lane = t & 63;
  const int li = lane & 15, grp = lane >> 4;
  const int m0 = mb * 128 + (wave >> 1) * 64;
  const int n0 = nb * 64 + (wave & 1) * 32;
  const bool swap = (!PROJ) && (mb >= 4);
  const int Mt0 = m0 >> 4;
  const int Nt0 = b * 64 + (n0 >> 4);
  const s16x8* __restrict__ Af = (const s16x8*)Wp;
  const s16x8* __restrict__ Bf = (const s16x8*)Bp;

  f32x4 acc[4][2];
#pragma unroll
  for (int mt = 0; mt < 4; ++mt)
#pragma unroll
    for (int nt = 0; nt < 2; ++nt) acc[mt][nt] = f32x4{0.f, 0.f, 0.f, 0.f};

#pragma unroll 2
  for (int kt = 0; kt < 8; ++kt) {
    s16x8 a[4], bb[2];
#pragma unroll
    for (int mt = 0; mt < 4; ++mt)
      a[mt] = Af[((size_t)(Mt0 + mt) * 8 + kt) * 64 + lane];
#pragma unroll
    for (int nt = 0; nt < 2; ++nt)
      bb[nt] = Bf[((size_t)(Nt0 + nt) * 8 + kt) * 64 + lane];
    if (swap) {
#pragma unroll
      for (int mt = 0; mt < 4; ++mt)
#pragma unroll
        for (int nt = 0; nt < 2; ++nt)
          acc[mt][nt] = mfma16(bb[nt], a[mt], acc[mt][nt]);
    } else {
#pragma unroll
      for (int mt = 0; mt < 4; ++mt)
#pragma unroll
        for (int nt = 0; nt < 2; ++nt)
          acc[mt][nt] = mfma16(a[mt], bb[nt], acc[mt][nt]);
    }
  }

  if (PROJ) {
    // D[m=ch rows 4grp+r][n=pos col li]; fp32 out + bias + residual
#pragma unroll
    for (int mt = 0; mt < 4; ++mt) {
      const int mbase = m0 + mt * 16 + 4 * grp;
      const float4 bv = *(const float4*)(bias + mbase);
      const float bvr[4] = {bv.x, bv.y, bv.z, bv.w};
#pragma unroll
      for (int nt = 0; nt < 2; ++nt) {
        const int pos = n0 + nt * 16 + li;
#pragma unroll
        for (int r = 0; r < 4; ++r) {
          const size_t ob = ((size_t)(b * 256 + mbase + r)) * 1024 + pos;
          outp[ob] = acc[mt][nt][r] + bvr[r] + res[ob];
        }
      }
    }
  } else if (!swap) {
    // Q/K: D rows = ch (4grp+r), cols = pos (li). Pack to Qp/Kp frag layout.
    unsigned short* __restrict__ Tp = (mb < 2) ? Qp : Kp;
#pragma unroll
    for (int mt = 0; mt < 4; ++mt) {
      const int mbase = m0 + mt * 16;
      const int head = (mbase >> 6) & 3;
      const int bh = b * 4 + head;
      const int c16 = mbase & 63;                    // 16-aligned
      const int ks = c16 >> 5;
      const int grpp = ((c16 >> 3) + (grp >> 1)) & 3;
      const float4 bv = *(const float4*)(bias + mbase + 4 * grp);
#pragma unroll
      for (int nt = 0; nt < 2; ++nt) {
        const int pt = (n0 >> 4) + nt;
        ushort4 o;
        o.x = f2bf(acc[mt][nt][0] + bv.x);
        o.y = f2bf(acc[mt][nt][1] + bv.y);
        o.z = f2bf(acc[mt][nt][2] + bv.z);
        o.w = f2bf(acc[mt][nt][3] + bv.w);
        *(ushort4*)(Tp + (size_t)bh * 65536 +
                    ((size_t)(pt * 2 + ks) * 64 + grpp * 16 + li) * 8 +
                    (grp & 1) * 4) = o;
      }
    }
  } else {
    // V: D rows = pos (4grp+r), cols = ch (li). Pack to Vp frag layout.
#pragma unroll
    for (int mt = 0; mt < 4; ++mt) {
      const int mbase = m0 + mt * 16;
      const int head = (mbase >> 6) & 3;
      const int bh = b * 4 + head;
      const int ct = (mbase & 63) >> 4;
      const float bvc = bias[mbase + li];            // per-column bias
      const int kvt = n0 >> 5;
#pragma unroll
      for (int nt = 0; nt < 2; ++nt) {
        const int grpv = (nt * 2 + (grp >> 1)) & 3;
        ushort4 o;
        o.x = f2bf(acc[mt][nt][0] + bvc);
        o.y = f2bf(acc[mt][nt][1] + bvc);
        o.z = f2bf(acc[mt][nt][2] + bvc);
        o.w = f2bf(acc[mt][nt][3] + bvc);
        *(ushort4*)(Vp + (size_t)bh * 65536 +
                    ((size_t)(ct * 32 + kvt) * 64 + grpv * 16 + li) * 8 +
                    (grp & 1) * 4) = o;
      }
    }
  }
}

// ---------------------------------------------------------------------------
// MFMA flash attention, packed-frag I/O. 4 indep waves/block, 16 q each.
// XCD-chunked swizzle keeps each bh's K/V on one XCD's L2.
// ---------------------------------------------------------------------------
__global__ __launch_bounds__(256) void attn_mfma_kernel(
    const unsigned short* __restrict__ Qp, const unsigned short* __restrict__ Kp,
    const unsigned short* __restrict__ Vp, unsigned short* __restrict__ aoTp) {
  __shared__ unsigned short P_lds[4][16][56];
  const int bid = blockIdx.x;
  const int swz = (bid & 7) * 64 + (bid >> 3);   // 512 = 8 * 64, bijective
  const int bh = swz >> 4, qb = swz & 15;
  const int b = bh >> 2, head = bh & 3;
  const int t = threadIdx.x;
  const int wave = t >> 6, lane = t & 63;
  const int li = lane & 15, grp = lane >> 4;
  const int q0 = qb * 64 + wave * 16;
  const unsigned short* __restrict__ Qb = Qp + (size_t)bh * 65536;
  const unsigned short* __restrict__ Kb = Kp + (size_t)bh * 65536;
  const unsigned short* __restrict__ Vb = Vp + (size_t)bh * 65536;

  s16x8 qf[2];
#pragma unroll
  for (int ks = 0; ks < 2; ++ks)
    qf[ks] = *(const s16x8*)(Qb + (((q0 >> 4) * 2 + ks) * 64 + lane) * 8);

  f32x4 O[4];
#pragma unroll
  for (int ct = 0; ct < 4; ++ct) O[ct] = f32x4{0.f, 0.f, 0.f, 0.f};
  float m_run = -3.0e38f, l_run = 0.f;

  s16x8 kf[2][2];
#pragma unroll
  for (int mt = 0; mt < 2; ++mt)
#pragma unroll
    for (int ks = 0; ks < 2; ++ks)
      kf[mt][ks] = *(const s16x8*)(Kb + ((size_t)(mt * 2 + ks) * 64 + lane) * 8);

  for (int it = 0; it < 32; ++it) {
    // V frags (coalesced; waited at the PV mfma)
    s16x8 vf[4];
#pragma unroll
    for (int ct = 0; ct < 4; ++ct)
      vf[ct] = *(const s16x8*)(Vb + ((size_t)(ct * 32 + it) * 64 + lane) * 8);
    // prefetch next K frags
    s16x8 kn[2][2];
    if (it < 31) {
#pragma unroll
      for (int mt = 0; mt < 2; ++mt)
#pragma unroll
        for (int ks = 0; ks < 2; ++ks)
          kn[mt][ks] = *(const s16x8*)(
              Kb + ((size_t)(((it + 1) * 2 + mt) * 2 + ks) * 64 + lane) * 8);
    }
    // S^T = K-tile . Q-tile (rows j, col q)
    f32x4 s[2];
#pragma unroll
    for (int mt = 0; mt < 2; ++mt) {
      s[mt] = mfma16(kf[mt][0], qf[0], f32x4{0.f, 0.f, 0.f, 0.f});
      s[mt] = mfma16(kf[mt][1], qf[1], s[mt]);
    }
    // online softmax (scale 1/8 folded into exp args)
    float pm = fmaxf(fmaxf(fmaxf(s[0][0], s[0][1]), fmaxf(s[0][2], s[0][3])),
                     fmaxf(fmaxf(s[1][0], s[1][1]), fmaxf(s[1][2], s[1][3])));
    pm = fmaxf(pm, __shfl_xor(pm, 16));
    pm = fmaxf(pm, __shfl_xor(pm, 32));
    const float mnew = fmaxf(m_run, pm);
    const float f = __expf((m_run - mnew) * 0.125f);
    m_run = mnew;
    l_run *= f;
#pragma unroll
    for (int ct = 0; ct < 4; ++ct) O[ct] *= f;
    float p[2][4];
#pragma unroll
    for (int mt = 0; mt < 2; ++mt)
#pragma unroll
      for (int r = 0; r < 4; ++r) {
        p[mt][r] = __expf((s[mt][r] - mnew) * 0.125f);
        l_run += p[mt][r];
      }
    // pack P -> per-wave LDS at [q][j], j = 16*mt + 4*grp + reg
#pragma unroll
    for (int mt = 0; mt < 2; ++mt) {
      ushort4 w4;
      w4.x = f2bf(p[mt][0]);
      w4.y = f2bf(p[mt][1]);
      w4.z = f2bf(p[mt][2]);
      w4.w = f2bf(p[mt][3]);
      *(ushort4*)&P_lds[wave][li][16 * mt + 4 * grp] = w4;
    }
    const s16x8 pf = *(const s16x8*)&P_lds[wave][li][8 * grp];
#pragma unroll
    for (int ct = 0; ct < 4; ++ct)
      O[ct] = mfma16(vf[ct], pf, O[ct]);
#pragma unroll
    for (int mt = 0; mt < 2; ++mt)
#pragma unroll
      for (int ks = 0; ks < 2; ++ks)
        kf[mt][ks] = kn[mt][ks];
  }

  float lt = l_run;
  lt += __shfl_xor(lt, 16);
  lt += __shfl_xor(lt, 32);
  const float rinv = 1.f / lt;
  // write aoTp packed frags: q = q0+li, c = head*64 + ct*16 + 4*grp + r
#pragma unroll
  for (int ct = 0; ct < 4; ++ct) {
    const int ktp = head * 2 + (ct >> 1);
    const int grpp = ((ct & 1) * 2 + (grp >> 1)) & 3;
    ushort4 o;
    o.x = f2bf(O[ct][0] * rinv);
    o.y = f2bf(O[ct][1] * rinv);
    o.z = f2bf(O[ct][2] * rinv);
    o.w = f2bf(O[ct][3] * rinv);
    *(ushort4*)(aoTp +
                ((size_t)((b * 64 + (q0 >> 4)) * 8 + ktp) * 64 + grpp * 16 + li) * 8 +
                (grp & 1) * 4) = o;
  }
}

// ---------------------------------------------------------------------------
extern "C" void kernel_launch(void* const* d_in, const int* in_sizes, int n_in,
                              void* d_out, int out_size, void* d_ws, size_t ws_size,
                              hipStream_t stream) {
  const float* x      = (const float*)d_in[0];
  const float* gamma  = (const float*)d_in[1];
  const float* beta   = (const float*)d_in[2];
  const float* w_qkv  = (const float*)d_in[3];
  const float* b_qkv  = (const float*)d_in[4];
  const float* w_proj = (const float*)d_in[5];
  const float* b_proj = (const float*)d_in[6];
  float* out = (float*)d_out;

  unsigned short* ws = (unsigned short*)d_ws;
  unsigned short* Wqp  = ws;                    // 196608
  unsigned short* Wpp  = Wqp + 196608;          // 65536
  unsigned short* hTp  = Wpp + 65536;           // 2097152
  unsigned short* Qp   = hTp + 2097152;         // 2097152
  unsigned short* Kp   = Qp + 2097152;          // 2097152
  unsigned short* Vp   = Kp + 2097152;          // 2097152
  unsigned short* aoTp = Vp + 2097152;          // 2097152

  hipLaunchKernelGGL(pack_w_kernel, dim3(128), dim3(256), 0, stream,
                     w_qkv, w_proj, Wqp, Wpp);
  hipLaunchKernelGGL(gn_kernel, dim3(256), dim3(256), 0, stream,
                     x, gamma, beta, hTp);
  hipLaunchKernelGGL((gemm_pk_kernel<6, false>), dim3(768), dim3(256), 0, stream,
                     Wqp, b_qkv, hTp, Qp, Kp, Vp, nullptr, nullptr);
  hipLaunchKernelGGL(attn_mfma_kernel, dim3(512), dim3(256), 0, stream,
                     Qp, Kp, Vp, aoTp);
  hipLaunchKernelGGL((gemm_pk_kernel<2, true>), dim3(256), dim3(256), 0, stream,
                     Wpp, b_proj, aoTp, nullptr, nullptr, nullptr, x, out);
}

// Round 4
// 50.052 us; speedup vs baseline: 7.6990x; 1.0554x over previous
//
#include <hip/hip_runtime.h>
#include <hip/hip_bf16.h>

static constexpr int kB = 8;
static constexpr int kC = 256;
static constexpr int kN = 1024;   // H*W
static constexpr int kHD = 64;

using s16x8 = __attribute__((ext_vector_type(8))) short;
using f32x4 = __attribute__((ext_vector_type(4))) float;

__device__ inline f32x4 mfma16(s16x8 a, s16x8 b, f32x4 c) {
  return __builtin_amdgcn_mfma_f32_16x16x32_bf16(a, b, c, 0, 0, 0);
}

__device__ inline unsigned short f2bf(float f) {   // RNE
  unsigned u = __builtin_bit_cast(unsigned, f);
  u = (u + 0x7fffu + ((u >> 16) & 1u)) >> 16;
  return (unsigned short)u;
}

__device__ inline float exp2_fast(float x) {   // 2^x, single v_exp_f32
  float r;
  asm("v_exp_f32 %0, %1" : "=v"(r) : "v"(x));
  return r;
}

__device__ inline unsigned cvt_pk_bf16(float lo, float hi) {   // packed RNE bf16 pair
  unsigned r;
  asm("v_cvt_pk_bf16_f32 %0, %1, %2" : "=v"(r) : "v"(lo), "v"(hi));
  return r;
}

// 1/sqrt(64) * log2(e): folded into Q so QK^T lands in exp2 units.
static constexpr float kQScale = 0.18033688011112042f;

// ---------------------------------------------------------------------------
// prep: blocks 0..127 pack weights into A-frag layout; blocks 128..383 GN.
//   W frag(Mt,kt): lane(li,grp) holds W[Mt*16+li][kt*32+grp*8 .. +8]
//   hTp frag(b,nt,kt): lane(li,grp) holds h[b][kt*32+grp*8..+8][nt*16+li]
// ---------------------------------------------------------------------------
__global__ __launch_bounds__(256) void prep_kernel(
    const float* __restrict__ x, const float* __restrict__ gamma,
    const float* __restrict__ beta, unsigned short* __restrict__ hTp,
    const float* __restrict__ wq, const float* __restrict__ wp,
    unsigned short* __restrict__ Wqp, unsigned short* __restrict__ Wpp) {
  if (blockIdx.x < 128) {
    const int tid = blockIdx.x * 256 + threadIdx.x;   // 0..32767
    const float* src;
    unsigned short* dst;
    if (tid < 24576) {
      const int fragid = tid >> 6, lane = tid & 63;
      const int Mt = fragid >> 3, kt = fragid & 7;
      const int li = lane & 15, g = lane >> 4;
      src = wq + (size_t)(Mt * 16 + li) * 256 + kt * 32 + g * 8;
      dst = Wqp + (size_t)tid * 8;
    } else {
      const int id = tid - 24576;
      const int fragid = id >> 6, lane = id & 63;
      const int Mt = fragid >> 3, kt = fragid & 7;
      const int li = lane & 15, g = lane >> 4;
      src = wp + (size_t)(Mt * 16 + li) * 256 + kt * 32 + g * 8;
      dst = Wpp + (size_t)id * 8;
    }
    const float4 f0 = *(const float4*)src;
    const float4 f1 = *(const float4*)(src + 4);
    ushort4 o0, o1;
    o0.x = f2bf(f0.x); o0.y = f2bf(f0.y); o0.z = f2bf(f0.z); o0.w = f2bf(f0.w);
    o1.x = f2bf(f1.x); o1.y = f2bf(f1.y); o1.z = f2bf(f1.z); o1.w = f2bf(f1.w);
    *(ushort4*)dst = o0;
    *(ushort4*)(dst + 4) = o1;
    return;
  }

  const int bg = blockIdx.x - 128;
  const int b = bg >> 5, g = bg & 31;
  const size_t base = ((size_t)b * kC + (size_t)g * 8) * kN;
  const float4* __restrict__ x4 = (const float4*)(x + base);
  const int t = threadIdx.x;

  float vv[8][4];
  float s = 0.f, ss = 0.f;
#pragma unroll
  for (int i = 0; i < 8; ++i) {
    const float4 v = x4[t + 256 * i];
    vv[i][0] = v.x; vv[i][1] = v.y; vv[i][2] = v.z; vv[i][3] = v.w;
    s += v.x + v.y + v.z + v.w;
    ss += v.x * v.x + v.y * v.y + v.z * v.z + v.w * v.w;
  }
#pragma unroll
  for (int off = 32; off > 0; off >>= 1) {
    s += __shfl_xor(s, off);
    ss += __shfl_xor(ss, off);
  }
  __shared__ float rs[4], rss[4];
  const int wave = t >> 6, lane = t & 63;
  if (lane == 0) { rs[wave] = s; rss[wave] = ss; }
  __syncthreads();
  s = rs[0] + rs[1] + rs[2] + rs[3];
  ss = rss[0] + rss[1] + rss[2] + rss[3];
  const float mean = s * (1.f / 8192.f);
  const float var = ss * (1.f / 8192.f) - mean * mean;
  const float rinv = rsqrtf(var + 1e-5f);
  float ga[8], be[8];
#pragma unroll
  for (int i = 0; i < 8; ++i) {
    ga[i] = gamma[g * 8 + i] * rinv;
    be[i] = beta[g * 8 + i] - mean * ga[i];
  }
  const int kt = g >> 2, gq = g & 3;
#pragma unroll
  for (int r = 0; r < 4; ++r) {
    const int pos = 4 * t + r;
    const int nt = pos >> 4, lp = pos & 15;
    unsigned short* dst =
        hTp + ((size_t)((b * 64 + nt) * 8 + kt) * 64 + (gq * 16 + lp)) * 8;
    ushort4 o0, o1;
    o0.x = f2bf(vv[0][r] * ga[0] + be[0]);
    o0.y = f2bf(vv[1][r] * ga[1] + be[1]);
    o0.z = f2bf(vv[2][r] * ga[2] + be[2]);
    o0.w = f2bf(vv[3][r] * ga[3] + be[3]);
    o1.x = f2bf(vv[4][r] * ga[4] + be[4]);
    o1.y = f2bf(vv[5][r] * ga[5] + be[5]);
    o1.z = f2bf(vv[6][r] * ga[6] + be[6]);
    o1.w = f2bf(vv[7][r] * ga[7] + be[7]);
    *(ushort4*)dst = o0;
    *(ushort4*)(dst + 4) = o1;
  }
}

// ---------------------------------------------------------------------------
// LDS-free bf16 MFMA GEMM with register double-buffer prefetch.
// Block: 4 waves (2m x 2n), tile 128m x 64n; wave 64m x 32n; K=256.
// ---------------------------------------------------------------------------
__device__ inline void gload(const s16x8* __restrict__ Af,
                             const s16x8* __restrict__ Bf,
                             int Mt0, int Nt0, int kt, int lane,
                             s16x8 (&a)[4], s16x8 (&bb)[2]) {
#pragma unroll
  for (int mt = 0; mt < 4; ++mt)
    a[mt] = Af[((size_t)(Mt0 + mt) * 8 + kt) * 64 + lane];
#pragma unroll
  for (int nt = 0; nt < 2; ++nt)
    bb[nt] = Bf[((size_t)(Nt0 + nt) * 8 + kt) * 64 + lane];
}

__device__ inline void gmfma(const s16x8 (&a)[4], const s16x8 (&bb)[2],
                             f32x4 (&acc)[4][2], bool swap) {
  if (swap) {
#pragma unroll
    for (int mt = 0; mt < 4; ++mt)
#pragma unroll
      for (int nt = 0; nt < 2; ++nt)
        acc[mt][nt] = mfma16(bb[nt], a[mt], acc[mt][nt]);
  } else {
#pragma unroll
    for (int mt = 0; mt < 4; ++mt)
#pragma unroll
      for (int nt = 0; nt < 2; ++nt)
        acc[mt][nt] = mfma16(a[mt], bb[nt], acc[mt][nt]);
  }
}

template <int MT128, bool PROJ>
__global__ __launch_bounds__(256) void gemm_pk_kernel(
    const unsigned short* __restrict__ Wp, const float* __restrict__ bias,
    const unsigned short* __restrict__ Bp,
    unsigned short* __restrict__ Qp, unsigned short* __restrict__ Kp,
    unsigned short* __restrict__ Vp,
    const float* __restrict__ res, float* __restrict__ outp) {
  constexpr int CPX = MT128 * 16;
  const int bid = blockIdx.x;
  const int swz = (bid & 7) * CPX + (bid >> 3);
  const int b = swz / CPX, rr = swz % CPX;
  const int mb = rr >> 4, nb = rr & 15;
  const int t = threadIdx.x;
  const int wave = t >> 6, lane = t & 63;
  const int li = lane & 15, grp = lane >> 4;
  const int m0 = mb * 128 + (wave >> 1) * 64;
  const int n0 = nb * 64 + (wave & 1) * 32;
  const bool swap = (!PROJ) && (mb >= 4);
  const int Mt0 = m0 >> 4;
  const int Nt0 = b * 64 + (n0 >> 4);
  const s16x8* __restrict__ Af = (const s16x8*)Wp;
  const s16x8* __restrict__ Bf = (const s16x8*)Bp;

  f32x4 acc[4][2];
#pragma unroll
  for (int mt = 0; mt < 4; ++mt)
#pragma unroll
    for (int nt = 0; nt < 2; ++nt) acc[mt][nt] = f32x4{0.f, 0.f, 0.f, 0.f};

  s16x8 aA[4], bA[2], aB[4], bB[2];
  gload(Af, Bf, Mt0, Nt0, 0, lane, aA, bA);
#pragma unroll
  for (int kt = 0; kt < 8; kt += 2) {
    if (kt + 1 < 8) gload(Af, Bf, Mt0, Nt0, kt + 1, lane, aB, bB);
    gmfma(aA, bA, acc, swap);
    if (kt + 2 < 8) gload(Af, Bf, Mt0, Nt0, kt + 2, lane, aA, bA);
    gmfma(aB, bB, acc, swap);
  }

  if (PROJ) {
#pragma unroll
    for (int mt = 0; mt < 4; ++mt) {
      const int mbase = m0 + mt * 16 + 4 * grp;
      const float4 bv = *(const float4*)(bias + mbase);
      const float bvr[4] = {bv.x, bv.y, bv.z, bv.w};
#pragma unroll
      for (int nt = 0; nt < 2; ++nt) {
        const int pos = n0 + nt * 16 + li;
#pragma unroll
        for (int r = 0; r < 4; ++r) {
          const size_t ob = ((size_t)(b * 256 + mbase + r)) * 1024 + pos;
          outp[ob] = acc[mt][nt][r] + bvr[r] + res[ob];
        }
      }
    }
  } else if (!swap) {
    // Q/K: D rows = ch (4grp+r), cols = pos (li). Q gets kQScale folded in.
    unsigned short* __restrict__ Tp = (mb < 2) ? Qp : Kp;
    const float qs = (mb < 2) ? kQScale : 1.0f;
#pragma unroll
    for (int mt = 0; mt < 4; ++mt) {
      const int mbase = m0 + mt * 16;
      const int head = (mbase >> 6) & 3;
      const int bh = b * 4 + head;
      const int c16 = mbase & 63;
      const int ks = c16 >> 5;
      const int grpp = ((c16 >> 3) + (grp >> 1)) & 3;
      const float4 bv = *(const float4*)(bias + mbase + 4 * grp);
#pragma unroll
      for (int nt = 0; nt < 2; ++nt) {
        const int pt = (n0 >> 4) + nt;
        ushort4 o;
        o.x = f2bf((acc[mt][nt][0] + bv.x) * qs);
        o.y = f2bf((acc[mt][nt][1] + bv.y) * qs);
        o.z = f2bf((acc[mt][nt][2] + bv.z) * qs);
        o.w = f2bf((acc[mt][nt][3] + bv.w) * qs);
        *(ushort4*)(Tp + (size_t)bh * 65536 +
                    ((size_t)(pt * 2 + ks) * 64 + grpp * 16 + li) * 8 +
                    (grp & 1) * 4) = o;
      }
    }
  } else {
    // V: D rows = pos (4grp+r), cols = ch (li).
#pragma unroll
    for (int mt = 0; mt < 4; ++mt) {
      const int mbase = m0 + mt * 16;
      const int head = (mbase >> 6) & 3;
      const int bh = b * 4 + head;
      const int ct = (mbase & 63) >> 4;
      const float bvc = bias[mbase + li];
      const int kvt = n0 >> 5;
#pragma unroll
      for (int nt = 0; nt < 2; ++nt) {
        const int grpv = (nt * 2 + (grp >> 1)) & 3;
        ushort4 o;
        o.x = f2bf(acc[mt][nt][0] + bvc);
        o.y = f2bf(acc[mt][nt][1] + bvc);
        o.z = f2bf(acc[mt][nt][2] + bvc);
        o.w = f2bf(acc[mt][nt][3] + bvc);
        *(ushort4*)(Vp + (size_t)bh * 65536 +
                    ((size_t)(ct * 32 + kvt) * 64 + grpv * 16 + li) * 8 +
                    (grp & 1) * 4) = o;
      }
    }
  }
}

// ---------------------------------------------------------------------------
// MFMA flash attention. S arrives in exp2 units (kQScale folded into Q).
// Defer-max rescale (THR=8 in exp2 units), v_exp asm, cvt_pk P-packing,
// ping-pong K double-buffer, per-wave P staging in LDS.
// ---------------------------------------------------------------------------
__global__ __launch_bounds__(256) void attn_mfma_kernel(
    const unsigned short* __restrict__ Qp, const unsigned short* __restrict__ Kp,
    const unsigned short* __restrict__ Vp, unsigned short* __restrict__ aoTp) {
  __shared__ unsigned short P_lds[4][16][56];
  const int bid = blockIdx.x;
  const int swz = (bid & 7) * 64 + (bid >> 3);   // 512 = 8 * 64, bijective
  const int bh = swz >> 4, qb = swz & 15;
  const int b = bh >> 2, head = bh & 3;
  const int t = threadIdx.x;
  const int wave = t >> 6, lane = t & 63;
  const int li = lane & 15, grp = lane >> 4;
  const int q0 = qb * 64 + wave * 16;
  const unsigned short* __restrict__ Qb = Qp + (size_t)bh * 65536;
  const unsigned short* __restrict__ Kb = Kp + (size_t)bh * 65536;
  const unsigned short* __restrict__ Vb = Vp + (size_t)bh * 65536;

  s16x8 qf[2];
#pragma unroll
  for (int ks = 0; ks < 2; ++ks)
    qf[ks] = *(const s16x8*)(Qb + (((q0 >> 4) * 2 + ks) * 64 + lane) * 8);

  f32x4 O[4];
#pragma unroll
  for (int ct = 0; ct < 4; ++ct) O[ct] = f32x4{0.f, 0.f, 0.f, 0.f};
  f32x4 lvec = f32x4{0.f, 0.f, 0.f, 0.f};
  float m_run = -1.0e30f;

  s16x8 ka[2][2], kb2[2][2];
#pragma unroll
  for (int mt = 0; mt < 2; ++mt)
#pragma unroll
    for (int ks = 0; ks < 2; ++ks)
      ka[mt][ks] = *(const s16x8*)(Kb + ((size_t)(mt * 2 + ks) * 64 + lane) * 8);

  auto body = [&](int it, s16x8 (&kc)[2][2], s16x8 (&kn)[2][2]) {
    // V frags for this tile (issued early, waited at PV mfma)
    s16x8 vf[4];
#pragma unroll
    for (int ct = 0; ct < 4; ++ct)
      vf[ct] = *(const s16x8*)(Vb + ((size_t)(ct * 32 + it) * 64 + lane) * 8);
    // prefetch next K tile (it=31 reads into Vp region: allocated, unused)
#pragma unroll
    for (int mt = 0; mt < 2; ++mt)
#pragma unroll
      for (int ks = 0; ks < 2; ++ks)
        kn[mt][ks] = *(const s16x8*)(
            Kb + ((size_t)(((it + 1) * 2 + mt) * 2 + ks) * 64 + lane) * 8);
    // S^T = K-tile . Q-tile (rows j = 16mt+4grp+r, col q = li), exp2 units
    f32x4 s[2];
#pragma unroll
    for (int mt = 0; mt < 2; ++mt) {
      s[mt] = mfma16(kc[mt][0], qf[0], f32x4{0.f, 0.f, 0.f, 0.f});
      s[mt] = mfma16(kc[mt][1], qf[1], s[mt]);
    }
    // per-q max (v_max3 trees + 2 shuffles)
    const float A = fmaxf(fmaxf(s[0][0], s[0][1]), s[0][2]);
    const float B = fmaxf(fmaxf(s[0][3], s[1][0]), s[1][1]);
    const float C = fmaxf(fmaxf(s[1][2], s[1][3]), A);
    float pm = fmaxf(B, C);
    pm = fmaxf(pm, __shfl_xor(pm, 16));
    pm = fmaxf(pm, __shfl_xor(pm, 32));
    // defer-max: only rescale when some q's max grew by > 8 (P <= 2^8)
    if (!__all(pm <= m_run + 8.0f)) {
      const float mnew = fmaxf(m_run, pm);
      const float f = exp2_fast(m_run - mnew);
      m_run = mnew;
      lvec *= f;
#pragma unroll
      for (int ct = 0; ct < 4; ++ct) O[ct] *= f;
    }
    f32x4 p[2];
#pragma unroll
    for (int mt = 0; mt < 2; ++mt) {
#pragma unroll
      for (int r = 0; r < 4; ++r) p[mt][r] = exp2_fast(s[mt][r] - m_run);
      lvec += p[mt];
    }
    // pack P -> per-wave LDS at [q][j]; j = 16mt + 4grp + reg
#pragma unroll
    for (int mt = 0; mt < 2; ++mt) {
      uint2 cc;
      cc.x = cvt_pk_bf16(p[mt][0], p[mt][1]);
      cc.y = cvt_pk_bf16(p[mt][2], p[mt][3]);
      *(uint2*)&P_lds[wave][li][16 * mt + 4 * grp] = cc;
    }
    const s16x8 pf = *(const s16x8*)&P_lds[wave][li][8 * grp];
#pragma unroll
    for (int ct = 0; ct < 4; ++ct) O[ct] = mfma16(vf[ct], pf, O[ct]);
  };

#pragma unroll 1
  for (int h2 = 0; h2 < 16; ++h2) {
    body(2 * h2, ka, kb2);
    body(2 * h2 + 1, kb2, ka);
  }

  float lt = lvec[0] + lvec[1] + lvec[2] + lvec[3];
  lt += __shfl_xor(lt, 16);
  lt += __shfl_xor(lt, 32);
  const float rinv = 1.f / lt;
  // write aoTp packed frags: q = q0+li, c = head*64 + ct*16 + 4*grp + r
#pragma unroll
  for (int ct = 0; ct < 4; ++ct) {
    const int ktp = head * 2 + (ct >> 1);
    const int grpp = ((ct & 1) * 2 + (grp >> 1)) & 3;
    ushort4 o;
    o.x = f2bf(O[ct][0] * rinv);
    o.y = f2bf(O[ct][1] * rinv);
    o.z = f2bf(O[ct][2] * rinv);
    o.w = f2bf(O[ct][3] * rinv);
    *(ushort4*)(aoTp +
                ((size_t)((b * 64 + (q0 >> 4)) * 8 + ktp) * 64 + grpp * 16 + li) * 8 +
                (grp & 1) * 4) = o;
  }
}

// ---------------------------------------------------------------------------
extern "C" void kernel_launch(void* const* d_in, const int* in_sizes, int n_in,
                              void* d_out, int out_size, void* d_ws, size_t ws_size,
                              hipStream_t stream) {
  const float* x      = (const float*)d_in[0];
  const float* gamma  = (const float*)d_in[1];
  const float* beta   = (const float*)d_in[2];
  const float* w_qkv  = (const float*)d_in[3];
  const float* b_qkv  = (const float*)d_in[4];
  const float* w_proj = (const float*)d_in[5];
  const float* b_proj = (const float*)d_in[6];
  float* out = (float*)d_out;

  unsigned short* ws = (unsigned short*)d_ws;
  unsigned short* Wqp  = ws;                    // 196608
  unsigned short* Wpp  = Wqp + 196608;          // 65536
  unsigned short* hTp  = Wpp + 65536;           // 2097152
  unsigned short* Qp   = hTp + 2097152;         // 2097152
  unsigned short* Kp   = Qp + 2097152;          // 2097152
  unsigned short* Vp   = Kp + 2097152;          // 2097152
  unsigned short* aoTp = Vp + 2097152;          // 2097152

  hipLaunchKernelGGL(prep_kernel, dim3(384), dim3(256), 0, stream,
                     x, gamma, beta, hTp, w_qkv, w_proj, Wqp, Wpp);
  hipLaunchKernelGGL((gemm_pk_kernel<6, false>), dim3(768), dim3(256), 0, stream,
                     Wqp, b_qkv, hTp, Qp, Kp, Vp, nullptr, nullptr);
  hipLaunchKernelGGL(attn_mfma_kernel, dim3(512), dim3(256), 0, stream,
                     Qp, Kp, Vp, aoTp);
  hipLaunchKernelGGL((gemm_pk_kernel<2, true>), dim3(256), dim3(256), 0, stream,
                     Wpp, b_proj, aoTp, nullptr, nullptr, nullptr, x, out);
}